// Round 1
// baseline (948.500 us; speedup 1.0000x reference)
//
#include <hip/hip_runtime.h>
#include <hip/hip_bf16.h>
#include <math.h>

// Problem constants (MambaBlock reference)
#define BB 2
#define LL 1024
#define DM 1024
#define DI 1024
#define DS 16
#define KC 3
#define ROWS (BB * LL)   // 2048

static __device__ __forceinline__ float sp_f(float x) {
    // numerically stable softplus: max(x,0) + log1p(exp(-|x|))
    return fmaxf(x, 0.f) + log1pf(expf(-fabsf(x)));
}
static __device__ __forceinline__ float silu_f(float x) {
    return x / (1.f + expf(-x));
}

// ---------------------------------------------------------------------------
// Tiled fp32 GEMM: C[M,N] = epilogue(A[M,K] @ Bm[K,N])
// 64x64 tile, BK=16, 256 threads, 4x4 per-thread register tile.
// ACT: 0 = none, 1 = softplus.  HAS_BIAS adds bias[col].  HAS_RES adds res[r*N+c].
// M,N multiples of 64; K multiple of 16 (true for all call sites).
// ---------------------------------------------------------------------------
template <int ACT, bool HAS_BIAS, bool HAS_RES>
__global__ __launch_bounds__(256) void gemm_k(
    const float* __restrict__ A, const float* __restrict__ Bm,
    const float* __restrict__ bias, const float* __restrict__ res,
    float* __restrict__ C, int M, int N, int K)
{
    __shared__ float As[64][20];   // [m][k], padded: 80B rows keep 16B align, spread banks
    __shared__ float Bs[16][64];   // [k][n]

    const int tid = threadIdx.x;
    const int tx = tid & 15;        // col group (4 cols each)
    const int ty = tid >> 4;        // row group (4 rows each)
    const int row0 = blockIdx.y * 64;
    const int col0 = blockIdx.x * 64;

    // A-load mapping: 16 consecutive k per 16 lanes (coalesced 64B), 16 rows/pass
    const int lk = tid & 15, lr = tid >> 4;
    // B-load mapping: 64 consecutive n per 64 lanes (coalesced 256B), 4 k/pass
    const int lc = tid & 63, lkb = tid >> 6;

    float acc[4][4] = {};

    for (int k0 = 0; k0 < K; k0 += 16) {
#pragma unroll
        for (int p = 0; p < 4; ++p) {
            int r = lr + p * 16;
            As[r][lk] = A[(size_t)(row0 + r) * K + k0 + lk];
        }
#pragma unroll
        for (int p = 0; p < 4; ++p) {
            int kk = lkb + p * 4;
            Bs[kk][lc] = Bm[(size_t)(k0 + kk) * N + col0 + lc];
        }
        __syncthreads();
#pragma unroll
        for (int kk = 0; kk < 16; ++kk) {
            float a4[4], b4[4];
#pragma unroll
            for (int i = 0; i < 4; ++i) a4[i] = As[ty * 4 + i][kk];
#pragma unroll
            for (int j = 0; j < 4; ++j) b4[j] = Bs[kk][tx * 4 + j];
#pragma unroll
            for (int i = 0; i < 4; ++i)
#pragma unroll
                for (int j = 0; j < 4; ++j)
                    acc[i][j] = fmaf(a4[i], b4[j], acc[i][j]);
        }
        __syncthreads();
    }

#pragma unroll
    for (int i = 0; i < 4; ++i) {
        int r = row0 + ty * 4 + i;
#pragma unroll
        for (int j = 0; j < 4; ++j) {
            int c = col0 + tx * 4 + j;
            float v = acc[i][j];
            if (HAS_BIAS) v += bias[c];
            if (ACT == 1) v = sp_f(v);
            if (HAS_RES) v += res[(size_t)r * N + c];
            C[(size_t)r * N + c] = v;
        }
    }
}

// ---------------------------------------------------------------------------
// Depthwise conv1d (K=3, same padding within each batch) + SiLU.
// input: z[row, 0:DI] (row stride 2*DI), output val[row, c]
// ---------------------------------------------------------------------------
__global__ __launch_bounds__(256) void conv_silu_k(
    const float* __restrict__ z, const float* __restrict__ cw,
    float* __restrict__ val)
{
    int t = blockIdx.x * 256 + threadIdx.x;     // B*L*DI threads
    int c = t & (DI - 1);
    int row = t >> 10;                          // b*L + l
    int l = row & (LL - 1);
    float w0 = cw[c * 3 + 0], w1 = cw[c * 3 + 1], w2 = cw[c * 3 + 2];
    const float* zr = z + (size_t)row * (2 * DI) + c;
    float vm = (l > 0)      ? zr[-(ptrdiff_t)(2 * DI)] : 0.f;
    float v0 = zr[0];
    float vp = (l < LL - 1) ? zr[2 * DI] : 0.f;
    float s = vm * w0 + v0 * w1 + vp * w2;
    val[t] = silu_f(s);
}

// ---------------------------------------------------------------------------
// B/C projections: Bp[row,n] = val[row,:] . W_B[:,n]; same for Cp.
// thread per (row, j) with j in [0,32): j<16 -> B, else C.
// ---------------------------------------------------------------------------
__global__ __launch_bounds__(256) void proj_k(
    const float* __restrict__ val, const float* __restrict__ WB,
    const float* __restrict__ WC, float* __restrict__ Bp, float* __restrict__ Cp)
{
    int t = blockIdx.x * 256 + threadIdx.x;     // ROWS*32 threads
    int j = t & 31;
    int row = t >> 5;
    const float* W = (j < 16) ? WB : WC;
    int jj = j & 15;
    const float* v = val + (size_t)row * DI;
    float a0 = 0.f, a1 = 0.f, a2 = 0.f, a3 = 0.f;
#pragma unroll 4
    for (int k = 0; k < DI; k += 4) {
        a0 = fmaf(v[k + 0], W[(k + 0) * DS + jj], a0);
        a1 = fmaf(v[k + 1], W[(k + 1) * DS + jj], a1);
        a2 = fmaf(v[k + 2], W[(k + 2) * DS + jj], a2);
        a3 = fmaf(v[k + 3], W[(k + 3) * DS + jj], a3);
    }
    float acc = (a0 + a1) + (a2 + a3);
    if (j < 16) Bp[row * DS + jj] = acc;
    else        Cp[row * DS + jj] = acc;
}

// ---------------------------------------------------------------------------
// Selective scan. Thread per (b,d,n): h is a register; 16-lane reduce for y.
// ---------------------------------------------------------------------------
__global__ __launch_bounds__(256) void scan_k(
    const float* __restrict__ Delta, const float* __restrict__ val,
    const float* __restrict__ Bp, const float* __restrict__ Cp,
    const float* __restrict__ A_log, float* __restrict__ y)
{
    int t = blockIdx.x * 256 + threadIdx.x;     // BB*DI*DS = 32768 threads
    int n = t & (DS - 1);
    int d = (t >> 4) & (DI - 1);
    int b = t >> 14;

    float Adn = -expf(A_log[d * DS + n]);
    float h = 0.f;

    const float* Dp = Delta + (size_t)b * LL * DI + d;
    const float* up = val   + (size_t)b * LL * DI + d;
    const float* bp = Bp    + (size_t)b * LL * DS + n;
    const float* cp = Cp    + (size_t)b * LL * DS + n;
    float* yp       = y     + (size_t)b * LL * DI + d;

#pragma unroll 2
    for (int l = 0; l < LL; ++l) {
        float dv  = Dp[(size_t)l * DI];
        float u   = up[(size_t)l * DI];
        float bpl = bp[(size_t)l * DS];
        float cpl = cp[(size_t)l * DS];
        float dA = dv * Adn;
        float e  = expm1f(dA);
        float a  = e + 1.f;                    // == exp(dA)
        float bb = e / (dA + 1e-6f) * dv * bpl;
        h = a * h + bb * u;
        float p = h * cpl;
        p += __shfl_xor(p, 1);
        p += __shfl_xor(p, 2);
        p += __shfl_xor(p, 4);
        p += __shfl_xor(p, 8);
        if (n == 0) yp[(size_t)l * DI] = p;
    }
}

// ---------------------------------------------------------------------------
// g = y * silu(gate);  gate = z[row, DI + c]
// ---------------------------------------------------------------------------
__global__ __launch_bounds__(256) void gate_k(
    const float* __restrict__ y, const float* __restrict__ z,
    float* __restrict__ g)
{
    int t = blockIdx.x * 256 + threadIdx.x;     // B*L*DI
    int c = t & (DI - 1);
    int row = t >> 10;
    float gv = z[(size_t)row * (2 * DI) + DI + c];
    g[t] = y[t] * silu_f(gv);
}

// ---------------------------------------------------------------------------
extern "C" void kernel_launch(void* const* d_in, const int* in_sizes, int n_in,
                              void* d_out, int out_size, void* d_ws, size_t ws_size,
                              hipStream_t stream)
{
    (void)in_sizes; (void)n_in; (void)out_size; (void)ws_size;

    const float* x        = (const float*)d_in[0];
    const float* W_in     = (const float*)d_in[1];
    const float* conv_w   = (const float*)d_in[2];
    const float* W_B      = (const float*)d_in[3];
    const float* W_C      = (const float*)d_in[4];
    const float* W_delta  = (const float*)d_in[5];
    const float* delta_b  = (const float*)d_in[6];
    const float* W_tau    = (const float*)d_in[7];
    const float* A_log    = (const float*)d_in[8];
    const float* W_out    = (const float*)d_in[9];
    float* out = (float*)d_out;

    float* ws = (float*)d_ws;
    float* z        = ws;                        // ROWS*2*DI  = 4,194,304
    float* val      = z + (size_t)ROWS * 2 * DI; // ROWS*DI    = 2,097,152
    float* Bp       = val + (size_t)ROWS * DI;   // ROWS*DS
    float* Cp       = Bp + (size_t)ROWS * DS;    // ROWS*DS
    float* combined = Cp + (size_t)ROWS * DS;    // ROWS*DM
    float* Delta    = combined + (size_t)ROWS * DM;
    float* yb       = Delta + (size_t)ROWS * DM;
    float* g        = combined;                  // reuse (combined dead after Delta GEMM)

    // 1) z = x @ W_in   [2048 x 2048]
    gemm_k<0, false, false><<<dim3(2 * DI / 64, ROWS / 64), 256, 0, stream>>>(
        x, W_in, nullptr, nullptr, z, ROWS, 2 * DI, DM);

    // 2) val = silu(conv1d(z[:, :DI]))
    conv_silu_k<<<(ROWS * DI) / 256, 256, 0, stream>>>(z, conv_w, val);

    // 3) B/C projections
    proj_k<<<(ROWS * 32) / 256, 256, 0, stream>>>(val, W_B, W_C, Bp, Cp);

    // 4) combined = val @ W_delta + delta_base
    gemm_k<0, true, false><<<dim3(DM / 64, ROWS / 64), 256, 0, stream>>>(
        val, W_delta, delta_b, nullptr, combined, ROWS, DM, DI);

    // 5) Delta = softplus(combined @ W_tau)
    gemm_k<1, false, false><<<dim3(DM / 64, ROWS / 64), 256, 0, stream>>>(
        combined, W_tau, nullptr, nullptr, Delta, ROWS, DM, DM);

    // 6) selective scan -> yb
    scan_k<<<(BB * DI * DS) / 256, 256, 0, stream>>>(Delta, val, Bp, Cp, A_log, yb);

    // 7) g = yb * silu(gate)
    gate_k<<<(ROWS * DI) / 256, 256, 0, stream>>>(yb, z, g);

    // 8) out = g @ W_out + x
    gemm_k<0, false, true><<<dim3(DM / 64, ROWS / 64), 256, 0, stream>>>(
        g, W_out, nullptr, x, out, ROWS, DM, DI);
}

// Round 2
// 537.637 us; speedup vs baseline: 1.7642x; 1.7642x over previous
//
#include <hip/hip_runtime.h>
#include <hip/hip_bf16.h>
#include <math.h>

// Problem constants (MambaBlock reference)
#define BB 2
#define LL 1024
#define DM 1024
#define DI 1024
#define DS 16
#define ROWS (BB * LL)   // 2048

// chunked scan
#define CHUNK 32
#define NC (LL / CHUNK)  // 32

static __device__ __forceinline__ float sp_f(float x) {
    return fmaxf(x, 0.f) + log1pf(expf(-fabsf(x)));
}
static __device__ __forceinline__ float silu_f(float x) {
    return x / (1.f + expf(-x));
}

// ---------------------------------------------------------------------------
// Tiled fp32 GEMM: C[M,N] = epilogue(A[M,K] @ Bm[K,N])
// ---------------------------------------------------------------------------
template <int ACT, bool HAS_BIAS, bool HAS_RES>
__global__ __launch_bounds__(256) void gemm_k(
    const float* __restrict__ A, const float* __restrict__ Bm,
    const float* __restrict__ bias, const float* __restrict__ res,
    float* __restrict__ C, int M, int N, int K)
{
    __shared__ float As[64][20];
    __shared__ float Bs[16][64];

    const int tid = threadIdx.x;
    const int tx = tid & 15;
    const int ty = tid >> 4;
    const int row0 = blockIdx.y * 64;
    const int col0 = blockIdx.x * 64;

    const int lk = tid & 15, lr = tid >> 4;
    const int lc = tid & 63, lkb = tid >> 6;

    float acc[4][4] = {};

    for (int k0 = 0; k0 < K; k0 += 16) {
#pragma unroll
        for (int p = 0; p < 4; ++p) {
            int r = lr + p * 16;
            As[r][lk] = A[(size_t)(row0 + r) * K + k0 + lk];
        }
#pragma unroll
        for (int p = 0; p < 4; ++p) {
            int kk = lkb + p * 4;
            Bs[kk][lc] = Bm[(size_t)(k0 + kk) * N + col0 + lc];
        }
        __syncthreads();
#pragma unroll
        for (int kk = 0; kk < 16; ++kk) {
            float a4[4], b4[4];
#pragma unroll
            for (int i = 0; i < 4; ++i) a4[i] = As[ty * 4 + i][kk];
#pragma unroll
            for (int j = 0; j < 4; ++j) b4[j] = Bs[kk][tx * 4 + j];
#pragma unroll
            for (int i = 0; i < 4; ++i)
#pragma unroll
                for (int j = 0; j < 4; ++j)
                    acc[i][j] = fmaf(a4[i], b4[j], acc[i][j]);
        }
        __syncthreads();
    }

#pragma unroll
    for (int i = 0; i < 4; ++i) {
        int r = row0 + ty * 4 + i;
#pragma unroll
        for (int j = 0; j < 4; ++j) {
            int c = col0 + tx * 4 + j;
            float v = acc[i][j];
            if (HAS_BIAS) v += bias[c];
            if (ACT == 1) v = sp_f(v);
            if (HAS_RES) v += res[(size_t)r * N + c];
            C[(size_t)r * N + c] = v;
        }
    }
}

// ---------------------------------------------------------------------------
// Depthwise conv1d (K=3, same padding) + SiLU
// ---------------------------------------------------------------------------
__global__ __launch_bounds__(256) void conv_silu_k(
    const float* __restrict__ z, const float* __restrict__ cw,
    float* __restrict__ val)
{
    int t = blockIdx.x * 256 + threadIdx.x;
    int c = t & (DI - 1);
    int row = t >> 10;
    int l = row & (LL - 1);
    float w0 = cw[c * 3 + 0], w1 = cw[c * 3 + 1], w2 = cw[c * 3 + 2];
    const float* zr = z + (size_t)row * (2 * DI) + c;
    float vm = (l > 0)      ? zr[-(ptrdiff_t)(2 * DI)] : 0.f;
    float v0 = zr[0];
    float vp = (l < LL - 1) ? zr[2 * DI] : 0.f;
    float s = vm * w0 + v0 * w1 + vp * w2;
    val[t] = silu_f(s);
}

// ---------------------------------------------------------------------------
// B/C projections (N=16 each)
// ---------------------------------------------------------------------------
__global__ __launch_bounds__(256) void proj_k(
    const float* __restrict__ val, const float* __restrict__ WB,
    const float* __restrict__ WC, float* __restrict__ Bp, float* __restrict__ Cp)
{
    int t = blockIdx.x * 256 + threadIdx.x;
    int j = t & 31;
    int row = t >> 5;
    const float* W = (j < 16) ? WB : WC;
    int jj = j & 15;
    const float* v = val + (size_t)row * DI;
    float a0 = 0.f, a1 = 0.f, a2 = 0.f, a3 = 0.f;
#pragma unroll 4
    for (int k = 0; k < DI; k += 4) {
        a0 = fmaf(v[k + 0], W[(k + 0) * DS + jj], a0);
        a1 = fmaf(v[k + 1], W[(k + 1) * DS + jj], a1);
        a2 = fmaf(v[k + 2], W[(k + 2) * DS + jj], a2);
        a3 = fmaf(v[k + 3], W[(k + 3) * DS + jj], a3);
    }
    float acc = (a0 + a1) + (a2 + a3);
    if (j < 16) Bp[row * DS + jj] = acc;
    else        Cp[row * DS + jj] = acc;
}

// ---------------------------------------------------------------------------
// Chunked selective scan.
// chain = (b,d,n), NC chunks of CHUNK steps.
// phase 1: per (chain,chunk) local state with h_in = 0 -> (aprod, hloc)
// phase 2: per chain, sequential combine over chunks -> hin[b,c,d,n]
// phase 3: per (chain,chunk) recompute with correct h_in, emit y
// state layout: [b][c][d][n]
// ---------------------------------------------------------------------------
__global__ __launch_bounds__(256) void scan_p1_k(
    const float* __restrict__ Delta, const float* __restrict__ val,
    const float* __restrict__ Bp, const float* __restrict__ A_log,
    float* __restrict__ aprod_s, float* __restrict__ hloc_s)
{
    int t = blockIdx.x * 256 + threadIdx.x;   // BB*NC*DI*DS = 2^20
    int n = t & (DS - 1);
    int d = (t >> 4) & (DI - 1);
    int c = (t >> 14) & (NC - 1);
    int b = t >> 19;

    float Adn = -expf(A_log[d * DS + n]);
    int row0 = b * LL + c * CHUNK;
    const float* Dp = Delta + (size_t)row0 * DI + d;
    const float* up = val   + (size_t)row0 * DI + d;
    const float* bp = Bp    + (size_t)row0 * DS + n;

    float h = 0.f, ap = 1.f;
#pragma unroll 4
    for (int l = 0; l < CHUNK; ++l) {
        float dv  = Dp[(size_t)l * DI];
        float u   = up[(size_t)l * DI];
        float bpl = bp[(size_t)l * DS];
        float dA = dv * Adn;
        float e  = expm1f(dA);
        float a  = e + 1.f;
        float bb = e / (dA + 1e-6f) * dv * bpl;
        h = a * h + bb * u;
        ap *= a;
    }
    size_t sidx = (((size_t)b * NC + c) * DI + d) * DS + n;
    aprod_s[sidx] = ap;
    hloc_s[sidx] = h;
}

__global__ __launch_bounds__(256) void scan_p2_k(
    const float* __restrict__ aprod_s, const float* __restrict__ hloc_s,
    float* __restrict__ hin_s)
{
    int t = blockIdx.x * 256 + threadIdx.x;   // BB*DI*DS = 32768
    int dn = t & (DI * DS - 1);
    int b = t >> 14;
    float hin = 0.f;
    size_t base = (size_t)b * NC * DI * DS + dn;
#pragma unroll 8
    for (int c = 0; c < NC; ++c) {
        size_t idx = base + (size_t)c * DI * DS;
        hin_s[idx] = hin;
        hin = aprod_s[idx] * hin + hloc_s[idx];
    }
}

__global__ __launch_bounds__(256) void scan_p3_k(
    const float* __restrict__ Delta, const float* __restrict__ val,
    const float* __restrict__ Bp, const float* __restrict__ Cp,
    const float* __restrict__ A_log, const float* __restrict__ hin_s,
    float* __restrict__ y)
{
    int t = blockIdx.x * 256 + threadIdx.x;   // BB*NC*DI*DS = 2^20
    int n = t & (DS - 1);
    int d = (t >> 4) & (DI - 1);
    int c = (t >> 14) & (NC - 1);
    int b = t >> 19;

    float Adn = -expf(A_log[d * DS + n]);
    int row0 = b * LL + c * CHUNK;
    const float* Dp = Delta + (size_t)row0 * DI + d;
    const float* up = val   + (size_t)row0 * DI + d;
    const float* bp = Bp    + (size_t)row0 * DS + n;
    const float* cp = Cp    + (size_t)row0 * DS + n;
    float* yp       = y     + (size_t)row0 * DI + d;

    float h = hin_s[(((size_t)b * NC + c) * DI + d) * DS + n];
#pragma unroll 4
    for (int l = 0; l < CHUNK; ++l) {
        float dv  = Dp[(size_t)l * DI];
        float u   = up[(size_t)l * DI];
        float bpl = bp[(size_t)l * DS];
        float cpl = cp[(size_t)l * DS];
        float dA = dv * Adn;
        float e  = expm1f(dA);
        float a  = e + 1.f;
        float bb = e / (dA + 1e-6f) * dv * bpl;
        h = a * h + bb * u;
        float p = h * cpl;
        p += __shfl_xor(p, 1);
        p += __shfl_xor(p, 2);
        p += __shfl_xor(p, 4);
        p += __shfl_xor(p, 8);
        if (n == 0) yp[(size_t)l * DI] = p;
    }
}

// ---------------------------------------------------------------------------
// g = y * silu(gate)
// ---------------------------------------------------------------------------
__global__ __launch_bounds__(256) void gate_k(
    const float* __restrict__ y, const float* __restrict__ z,
    float* __restrict__ g)
{
    int t = blockIdx.x * 256 + threadIdx.x;
    int c = t & (DI - 1);
    int row = t >> 10;
    float gv = z[(size_t)row * (2 * DI) + DI + c];
    g[t] = y[t] * silu_f(gv);
}

// ---------------------------------------------------------------------------
extern "C" void kernel_launch(void* const* d_in, const int* in_sizes, int n_in,
                              void* d_out, int out_size, void* d_ws, size_t ws_size,
                              hipStream_t stream)
{
    (void)in_sizes; (void)n_in; (void)out_size; (void)ws_size;

    const float* x        = (const float*)d_in[0];
    const float* W_in     = (const float*)d_in[1];
    const float* conv_w   = (const float*)d_in[2];
    const float* W_B      = (const float*)d_in[3];
    const float* W_C      = (const float*)d_in[4];
    const float* W_delta  = (const float*)d_in[5];
    const float* delta_b  = (const float*)d_in[6];
    const float* W_tau    = (const float*)d_in[7];
    const float* A_log    = (const float*)d_in[8];
    const float* W_out    = (const float*)d_in[9];
    float* out = (float*)d_out;

    float* ws = (float*)d_ws;
    float* z        = ws;                          // ROWS*2*DI
    float* val      = z + (size_t)ROWS * 2 * DI;   // ROWS*DI
    float* Bp       = val + (size_t)ROWS * DI;     // ROWS*DS
    float* Cp       = Bp + (size_t)ROWS * DS;      // ROWS*DS
    float* combined = Cp + (size_t)ROWS * DS;      // ROWS*DM
    float* Delta    = combined + (size_t)ROWS * DM;// ROWS*DM
    float* yb       = Delta + (size_t)ROWS * DM;   // ROWS*DI
    float* aprod_s  = yb + (size_t)ROWS * DI;      // BB*NC*DI*DS = 1M
    float* hloc_s   = aprod_s + (size_t)BB * NC * DI * DS;
    float* hin_s    = hloc_s + (size_t)BB * NC * DI * DS;
    float* g        = combined;                    // reuse

    // 1) z = x @ W_in
    gemm_k<0, false, false><<<dim3(2 * DI / 64, ROWS / 64), 256, 0, stream>>>(
        x, W_in, nullptr, nullptr, z, ROWS, 2 * DI, DM);

    // 2) val = silu(conv1d(z[:, :DI]))
    conv_silu_k<<<(ROWS * DI) / 256, 256, 0, stream>>>(z, conv_w, val);

    // 3) B/C projections
    proj_k<<<(ROWS * 32) / 256, 256, 0, stream>>>(val, W_B, W_C, Bp, Cp);

    // 4) combined = val @ W_delta + delta_base
    gemm_k<0, true, false><<<dim3(DM / 64, ROWS / 64), 256, 0, stream>>>(
        val, W_delta, delta_b, nullptr, combined, ROWS, DM, DI);

    // 5) Delta = softplus(combined @ W_tau)
    gemm_k<1, false, false><<<dim3(DM / 64, ROWS / 64), 256, 0, stream>>>(
        combined, W_tau, nullptr, nullptr, Delta, ROWS, DM, DM);

    // 6) chunked selective scan -> yb
    scan_p1_k<<<(BB * NC * DI * DS) / 256, 256, 0, stream>>>(
        Delta, val, Bp, A_log, aprod_s, hloc_s);
    scan_p2_k<<<(BB * DI * DS) / 256, 256, 0, stream>>>(aprod_s, hloc_s, hin_s);
    scan_p3_k<<<(BB * NC * DI * DS) / 256, 256, 0, stream>>>(
        Delta, val, Bp, Cp, A_log, hin_s, yb);

    // 7) g = yb * silu(gate)
    gate_k<<<(ROWS * DI) / 256, 256, 0, stream>>>(yb, z, g);

    // 8) out = g @ W_out + x
    gemm_k<0, false, true><<<dim3(DM / 64, ROWS / 64), 256, 0, stream>>>(
        g, W_out, nullptr, x, out, ROWS, DM, DI);
}

// Round 3
// 306.443 us; speedup vs baseline: 3.0952x; 1.7544x over previous
//
#include <hip/hip_runtime.h>
#include <math.h>

// Problem constants (MambaBlock reference)
#define BB 2
#define LL 1024
#define DM 1024
#define DI 1024
#define DS 16
#define ROWS (BB * LL)   // 2048
#define CHUNK 32
#define NC (LL / CHUNK)  // 32

typedef unsigned short ushort_t;
typedef __attribute__((ext_vector_type(8))) short short8;
typedef __attribute__((ext_vector_type(4))) float f32x4;
typedef __attribute__((ext_vector_type(4))) float f4;
typedef __attribute__((ext_vector_type(4))) ushort_t us4;

static __device__ __forceinline__ float sp_f(float x) {
    return fmaxf(x, 0.f) + log1pf(expf(-fabsf(x)));
}
static __device__ __forceinline__ float silu_f(float x) {
    return x / (1.f + expf(-x));
}
static __device__ __forceinline__ ushort_t f2bf(float f) {
    unsigned u = __float_as_uint(f);
    u += 0x7fffu + ((u >> 16) & 1u);
    return (ushort_t)(u >> 16);
}

// LDS XOR swizzle (involution on bits 4,5 keyed by row bits 1,2 = addr bits 7,8):
// fragment ds_read_b128 becomes 2-way (free), staging writes stay min-cycle.
#define SWZ(L) ((L) ^ ((((L) >> 7) & 1) << 4) ^ ((((L) >> 8) & 1) << 5))

// ---------------------------------------------------------------------------
// bf16 MFMA GEMM: C[M,N] = epi(A[M,K] @ Bt[N,K]^T)
// 128x128 tile, BK=32, 256 threads (4 waves, 2x2), 4x4 16x16x32 frags/wave.
// Reg-staged LDS with swizzle; 2-phase prefetch loop.
// M,N multiples of 128; K multiple of 32.
// ---------------------------------------------------------------------------
template <int ACT, bool HAS_BIAS, bool HAS_RES, bool OUTBF>
__global__ __launch_bounds__(256) void gemm_bf_k(
    const ushort_t* __restrict__ A, const ushort_t* __restrict__ Bt,
    const float* __restrict__ bias, const float* __restrict__ res,
    void* __restrict__ Cout, int M, int N, int K)
{
    __shared__ __align__(16) char lsa[8192];   // A tile [128][32] bf16
    __shared__ __align__(16) char lsb[8192];   // Bt tile [128][32] bf16

    const int tid = threadIdx.x;
    const int lane = tid & 63;
    const int w = tid >> 6, wr = w >> 1, wc = w & 1;
    const int row0 = blockIdx.y * 128, col0 = blockIdx.x * 128;
    const int rl = lane & 15, q = lane >> 4;

    // staging mapping: thread t covers logical bytes [t*16, t*16+16) (+4096 pass 1)
    const int srow = tid >> 2, schunk = tid & 3;
    const int Pw0 = SWZ(tid * 16);
    const int Pw1 = SWZ(4096 + tid * 16);

    int LA[4], LB[4];
#pragma unroll
    for (int m = 0; m < 4; ++m) LA[m] = SWZ((wr * 64 + m * 16 + rl) * 64 + q * 16);
#pragma unroll
    for (int n = 0; n < 4; ++n) LB[n] = SWZ((wc * 64 + n * 16 + rl) * 64 + q * 16);

    const ushort_t* pA = A + (size_t)(row0 + srow) * K + schunk * 8;
    const ushort_t* pB = Bt + (size_t)(col0 + srow) * K + schunk * 8;
    const size_t rowskip = (size_t)64 * K;

    // prefetch K-tile 0
    short8 ra0 = *(const short8*)(pA);
    short8 ra1 = *(const short8*)(pA + rowskip);
    short8 rb0 = *(const short8*)(pB);
    short8 rb1 = *(const short8*)(pB + rowskip);

    f32x4 acc[4][4] = {};

    const int NT = K >> 5;
    for (int kt = 0; kt < NT; ++kt) {
        __syncthreads();                        // prior compute done with LDS
        *(short8*)(lsa + Pw0) = ra0;
        *(short8*)(lsa + Pw1) = ra1;
        *(short8*)(lsb + Pw0) = rb0;
        *(short8*)(lsb + Pw1) = rb1;
        __syncthreads();
        if (kt + 1 < NT) {                      // issue next-tile loads; latency hides under MFMA
            const ushort_t* nA = pA + (size_t)(kt + 1) * 32;
            const ushort_t* nB = pB + (size_t)(kt + 1) * 32;
            ra0 = *(const short8*)(nA);
            ra1 = *(const short8*)(nA + rowskip);
            rb0 = *(const short8*)(nB);
            rb1 = *(const short8*)(nB + rowskip);
        }
        short8 af[4], bfr[4];
#pragma unroll
        for (int m = 0; m < 4; ++m) af[m] = *(const short8*)(lsa + LA[m]);
#pragma unroll
        for (int n = 0; n < 4; ++n) bfr[n] = *(const short8*)(lsb + LB[n]);
#pragma unroll
        for (int m = 0; m < 4; ++m)
#pragma unroll
            for (int n = 0; n < 4; ++n)
                acc[m][n] = __builtin_amdgcn_mfma_f32_16x16x32_bf16(
                    af[m], bfr[n], acc[m][n], 0, 0, 0);
    }

    float bia[4];
    if (HAS_BIAS) {
#pragma unroll
        for (int n = 0; n < 4; ++n) bia[n] = bias[col0 + wc * 64 + n * 16 + rl];
    }
#pragma unroll
    for (int m = 0; m < 4; ++m) {
#pragma unroll
        for (int n = 0; n < 4; ++n) {
            int c = col0 + wc * 64 + n * 16 + rl;
#pragma unroll
            for (int i = 0; i < 4; ++i) {
                int r = row0 + wr * 64 + m * 16 + q * 4 + i;
                float v = acc[m][n][i];
                if (HAS_BIAS) v += bia[n];
                if (ACT == 1) v = sp_f(v);
                if (HAS_RES) v += res[(size_t)r * N + c];
                if (OUTBF) ((ushort_t*)Cout)[(size_t)r * N + c] = f2bf(v);
                else       ((float*)Cout)[(size_t)r * N + c] = v;
            }
        }
    }
}

// ---------------------------------------------------------------------------
// Transpose-convert: in[K][N] fp32 -> out[N][K] bf16
// ---------------------------------------------------------------------------
__global__ __launch_bounds__(256) void tconv_k(
    const float* __restrict__ in, ushort_t* __restrict__ out, int K, int N)
{
    __shared__ float t[32][33];
    int lx = threadIdx.x & 31, ly = threadIdx.x >> 5;
    int n0 = blockIdx.x * 32, k0 = blockIdx.y * 32;
#pragma unroll
    for (int i = 0; i < 32; i += 8)
        t[ly + i][lx] = in[(size_t)(k0 + ly + i) * N + n0 + lx];
    __syncthreads();
#pragma unroll
    for (int i = 0; i < 32; i += 8)
        out[(size_t)(n0 + ly + i) * K + k0 + lx] = f2bf(t[lx][ly + i]);
}

// elementwise fp32 -> bf16 (4 elems/thread)
__global__ __launch_bounds__(256) void cvt_bf_k(
    const float* __restrict__ in, ushort_t* __restrict__ out)
{
    int t = blockIdx.x * 256 + threadIdx.x;
    f4 v = ((const f4*)in)[t];
    us4 o;
    o.x = f2bf(v.x); o.y = f2bf(v.y); o.z = f2bf(v.z); o.w = f2bf(v.w);
    ((us4*)out)[t] = o;
}

// ---------------------------------------------------------------------------
// Depthwise conv1d (K=3, same padding) + SiLU; writes fp32 and bf16
// ---------------------------------------------------------------------------
__global__ __launch_bounds__(256) void conv_silu_k(
    const float* __restrict__ z, const float* __restrict__ cw,
    float* __restrict__ val, ushort_t* __restrict__ val_bf)
{
    int t = blockIdx.x * 256 + threadIdx.x;
    int c = t & (DI - 1);
    int row = t >> 10;
    int l = row & (LL - 1);
    float w0 = cw[c * 3 + 0], w1 = cw[c * 3 + 1], w2 = cw[c * 3 + 2];
    const float* zr = z + (size_t)row * (2 * DI) + c;
    float vm = (l > 0)      ? zr[-(ptrdiff_t)(2 * DI)] : 0.f;
    float v0 = zr[0];
    float vp = (l < LL - 1) ? zr[2 * DI] : 0.f;
    float s = silu_f(vm * w0 + v0 * w1 + vp * w2);
    val[t] = s;
    val_bf[t] = f2bf(s);
}

// ---------------------------------------------------------------------------
// B/C projections (N=16 each)
// ---------------------------------------------------------------------------
__global__ __launch_bounds__(256) void proj_k(
    const float* __restrict__ val, const float* __restrict__ WB,
    const float* __restrict__ WC, float* __restrict__ Bp, float* __restrict__ Cp)
{
    int t = blockIdx.x * 256 + threadIdx.x;
    int j = t & 31;
    int row = t >> 5;
    const float* W = (j < 16) ? WB : WC;
    int jj = j & 15;
    const float* v = val + (size_t)row * DI;
    float a0 = 0.f, a1 = 0.f, a2 = 0.f, a3 = 0.f;
#pragma unroll 4
    for (int k = 0; k < DI; k += 4) {
        a0 = fmaf(v[k + 0], W[(k + 0) * DS + jj], a0);
        a1 = fmaf(v[k + 1], W[(k + 1) * DS + jj], a1);
        a2 = fmaf(v[k + 2], W[(k + 2) * DS + jj], a2);
        a3 = fmaf(v[k + 3], W[(k + 3) * DS + jj], a3);
    }
    float acc = (a0 + a1) + (a2 + a3);
    if (j < 16) Bp[row * DS + jj] = acc;
    else        Cp[row * DS + jj] = acc;
}

// ---------------------------------------------------------------------------
// Chunked selective scan (3 phases) — see R1
// ---------------------------------------------------------------------------
__global__ __launch_bounds__(256) void scan_p1_k(
    const float* __restrict__ Delta, const float* __restrict__ val,
    const float* __restrict__ Bp, const float* __restrict__ A_log,
    float* __restrict__ aprod_s, float* __restrict__ hloc_s)
{
    int t = blockIdx.x * 256 + threadIdx.x;   // BB*NC*DI*DS
    int n = t & (DS - 1);
    int d = (t >> 4) & (DI - 1);
    int c = (t >> 14) & (NC - 1);
    int b = t >> 19;

    float Adn = -expf(A_log[d * DS + n]);
    int row0 = b * LL + c * CHUNK;
    const float* Dp = Delta + (size_t)row0 * DI + d;
    const float* up = val   + (size_t)row0 * DI + d;
    const float* bp = Bp    + (size_t)row0 * DS + n;

    float h = 0.f, ap = 1.f;
#pragma unroll 4
    for (int l = 0; l < CHUNK; ++l) {
        float dv  = Dp[(size_t)l * DI];
        float u   = up[(size_t)l * DI];
        float bpl = bp[(size_t)l * DS];
        float dA = dv * Adn;
        float e  = expm1f(dA);
        float a  = e + 1.f;
        float bb = e / (dA + 1e-6f) * dv * bpl;
        h = a * h + bb * u;
        ap *= a;
    }
    size_t sidx = (((size_t)b * NC + c) * DI + d) * DS + n;
    aprod_s[sidx] = ap;
    hloc_s[sidx] = h;
}

__global__ __launch_bounds__(256) void scan_p2_k(
    const float* __restrict__ aprod_s, const float* __restrict__ hloc_s,
    float* __restrict__ hin_s)
{
    int t = blockIdx.x * 256 + threadIdx.x;   // BB*DI*DS
    int dn = t & (DI * DS - 1);
    int b = t >> 14;
    float hin = 0.f;
    size_t base = (size_t)b * NC * DI * DS + dn;
#pragma unroll 8
    for (int c = 0; c < NC; ++c) {
        size_t idx = base + (size_t)c * DI * DS;
        hin_s[idx] = hin;
        hin = aprod_s[idx] * hin + hloc_s[idx];
    }
}

__global__ __launch_bounds__(256) void scan_p3_k(
    const float* __restrict__ Delta, const float* __restrict__ val,
    const float* __restrict__ Bp, const float* __restrict__ Cp,
    const float* __restrict__ A_log, const float* __restrict__ hin_s,
    float* __restrict__ y)
{
    int t = blockIdx.x * 256 + threadIdx.x;
    int n = t & (DS - 1);
    int d = (t >> 4) & (DI - 1);
    int c = (t >> 14) & (NC - 1);
    int b = t >> 19;

    float Adn = -expf(A_log[d * DS + n]);
    int row0 = b * LL + c * CHUNK;
    const float* Dp = Delta + (size_t)row0 * DI + d;
    const float* up = val   + (size_t)row0 * DI + d;
    const float* bp = Bp    + (size_t)row0 * DS + n;
    const float* cp = Cp    + (size_t)row0 * DS + n;
    float* yp       = y     + (size_t)row0 * DI + d;

    float h = hin_s[(((size_t)b * NC + c) * DI + d) * DS + n];
#pragma unroll 4
    for (int l = 0; l < CHUNK; ++l) {
        float dv  = Dp[(size_t)l * DI];
        float u   = up[(size_t)l * DI];
        float bpl = bp[(size_t)l * DS];
        float cpl = cp[(size_t)l * DS];
        float dA = dv * Adn;
        float e  = expm1f(dA);
        float a  = e + 1.f;
        float bb = e / (dA + 1e-6f) * dv * bpl;
        h = a * h + bb * u;
        float p = h * cpl;
        p += __shfl_xor(p, 1);
        p += __shfl_xor(p, 2);
        p += __shfl_xor(p, 4);
        p += __shfl_xor(p, 8);
        if (n == 0) yp[(size_t)l * DI] = p;
    }
}

// ---------------------------------------------------------------------------
// g_bf = bf16(y * silu(gate))
// ---------------------------------------------------------------------------
__global__ __launch_bounds__(256) void gate_k(
    const float* __restrict__ y, const float* __restrict__ z,
    ushort_t* __restrict__ g_bf)
{
    int t = blockIdx.x * 256 + threadIdx.x;
    int c = t & (DI - 1);
    int row = t >> 10;
    float gv = z[(size_t)row * (2 * DI) + DI + c];
    g_bf[t] = f2bf(y[t] * silu_f(gv));
}

// ---------------------------------------------------------------------------
extern "C" void kernel_launch(void* const* d_in, const int* in_sizes, int n_in,
                              void* d_out, int out_size, void* d_ws, size_t ws_size,
                              hipStream_t stream)
{
    (void)in_sizes; (void)n_in; (void)out_size; (void)ws_size;

    const float* x        = (const float*)d_in[0];
    const float* W_in     = (const float*)d_in[1];
    const float* conv_w   = (const float*)d_in[2];
    const float* W_B      = (const float*)d_in[3];
    const float* W_C      = (const float*)d_in[4];
    const float* W_delta  = (const float*)d_in[5];
    const float* delta_b  = (const float*)d_in[6];
    const float* W_tau    = (const float*)d_in[7];
    const float* A_log    = (const float*)d_in[8];
    const float* W_out    = (const float*)d_in[9];
    float* out = (float*)d_out;

    const size_t M1 = 1024 * 1024;
    float* ws = (float*)d_ws;
    float* z      = ws;                  // 4M fl
    float* val    = ws + 4 * M1;         // 2M
    float* Delta  = ws + 6 * M1;         // 2M
    float* aprod  = ws + 8 * M1;         // 1M  (dead after p2)
    float* hloc   = ws + 9 * M1;         // 1M  (dead after p2)
    float* yb     = ws + 8 * M1;         // 2M  (aliases aprod+hloc, written in p3)
    float* hin    = ws + 10 * M1;        // 1M
    float* Bp     = ws + 11 * M1;                    // 32K fl
    float* Cp     = ws + 11 * M1 + ROWS * DS;        // 32K fl
    ushort_t* bfb = (ushort_t*)(ws + 11 * M1 + 2 * ROWS * DS);
    ushort_t* x_bf   = bfb;              // 2M bf16 (reused as g_bf)
    ushort_t* g_bf   = bfb;
    ushort_t* val_bf = bfb + 2 * M1;     // 2M
    ushort_t* cmb_bf = bfb + 4 * M1;     // 2M
    ushort_t* WinT   = bfb + 6 * M1;     // 2M
    ushort_t* WdT    = bfb + 8 * M1;     // 1M
    ushort_t* WtT    = bfb + 9 * M1;     // 1M
    ushort_t* WoT    = bfb + 10 * M1;    // 1M

    // 0) convert x; transpose-convert weights to [N][K] bf16
    cvt_bf_k<<<(ROWS * DM / 4) / 256, 256, 0, stream>>>(x, x_bf);
    tconv_k<<<dim3(2 * DI / 32, DM / 32), 256, 0, stream>>>(W_in, WinT, DM, 2 * DI);
    tconv_k<<<dim3(DM / 32, DI / 32), 256, 0, stream>>>(W_delta, WdT, DI, DM);
    tconv_k<<<dim3(DM / 32, DM / 32), 256, 0, stream>>>(W_tau, WtT, DM, DM);
    tconv_k<<<dim3(DM / 32, DI / 32), 256, 0, stream>>>(W_out, WoT, DI, DM);

    // 1) z = x @ W_in (fp32 out)
    gemm_bf_k<0, false, false, false><<<dim3(2 * DI / 128, ROWS / 128), 256, 0, stream>>>(
        x_bf, WinT, nullptr, nullptr, z, ROWS, 2 * DI, DM);

    // 2) val = silu(conv1d(z[:, :DI]))  (fp32 + bf16)
    conv_silu_k<<<(ROWS * DI) / 256, 256, 0, stream>>>(z, conv_w, val, val_bf);

    // 3) B/C projections
    proj_k<<<(ROWS * 32) / 256, 256, 0, stream>>>(val, W_B, W_C, Bp, Cp);

    // 4) combined = val @ W_delta + delta_base (bf16 out)
    gemm_bf_k<0, true, false, true><<<dim3(DM / 128, ROWS / 128), 256, 0, stream>>>(
        val_bf, WdT, delta_b, nullptr, cmb_bf, ROWS, DM, DI);

    // 5) Delta = softplus(combined @ W_tau) (fp32 out)
    gemm_bf_k<1, false, false, false><<<dim3(DM / 128, ROWS / 128), 256, 0, stream>>>(
        cmb_bf, WtT, nullptr, nullptr, Delta, ROWS, DM, DM);

    // 6) chunked selective scan -> yb
    scan_p1_k<<<(BB * NC * DI * DS) / 256, 256, 0, stream>>>(
        Delta, val, Bp, A_log, aprod, hloc);
    scan_p2_k<<<(BB * DI * DS) / 256, 256, 0, stream>>>(aprod, hloc, hin);
    scan_p3_k<<<(BB * NC * DI * DS) / 256, 256, 0, stream>>>(
        Delta, val, Bp, Cp, A_log, hin, yb);

    // 7) g_bf = bf16(yb * silu(gate))
    gate_k<<<(ROWS * DI) / 256, 256, 0, stream>>>(yb, z, g_bf);

    // 8) out = g @ W_out + x (fp32 out)
    gemm_bf_k<0, false, true, false><<<dim3(DM / 128, ROWS / 128), 256, 0, stream>>>(
        g_bf, WoT, nullptr, x, out, ROWS, DM, DI);
}

// Round 5
// 256.440 us; speedup vs baseline: 3.6987x; 1.1950x over previous
//
#include <hip/hip_runtime.h>
#include <math.h>

// Problem constants (MambaBlock reference)
#define BB 2
#define LL 1024
#define DM 1024
#define DI 1024
#define DS 16
#define ROWS (BB * LL)   // 2048
#define CH 16            // scan chunk length
#define NCH (LL / CH)    // 64 chunks
#define NP 1152          // W_delta GEMM N padded: 1024 cmb + 16 B + 16 C + 96 zero

typedef unsigned short ushort_t;
typedef __attribute__((ext_vector_type(8))) short short8;
typedef __attribute__((ext_vector_type(4))) float f32x4;
typedef __attribute__((ext_vector_type(4))) float f4;
typedef __attribute__((ext_vector_type(4))) ushort_t us4;

static __device__ __forceinline__ float sp_f(float x) {
    return fmaxf(x, 0.f) + log1pf(expf(-fabsf(x)));
}
static __device__ __forceinline__ ushort_t f2bf(float f) {
    unsigned u = __float_as_uint(f);
    u += 0x7fffu + ((u >> 16) & 1u);
    return (ushort_t)(u >> 16);
}
static __device__ __forceinline__ float bf2f(ushort_t s) {
    return __uint_as_float(((unsigned)s) << 16);
}

// LDS XOR swizzle (involution on bits 4,5 keyed by addr bits 7,8)
#define SWZ(L) ((L) ^ ((((L) >> 7) & 1) << 4) ^ ((((L) >> 8) & 1) << 5))

// ---------------------------------------------------------------------------
// bf16 MFMA GEMM: C[M,N] = epi(A[M,K] @ Bt[N,K]^T)
// 128x128 tile, BK=32, 256 threads (4 waves 2x2), 4x4 16x16x32 frags/wave.
// PROJ: cols [DM,DM+DS) -> BpO, [DM+DS,DM+2DS) -> CpO (fp32), rest >= DM dropped.
// ---------------------------------------------------------------------------
template <int ACT, bool HAS_BIAS, bool HAS_RES, bool OUTBF, bool PROJ>
__global__ __launch_bounds__(256) void gemm_bf_k(
    const ushort_t* __restrict__ A, const ushort_t* __restrict__ Bt,
    const float* __restrict__ bias, const float* __restrict__ res,
    void* __restrict__ Cout, float* __restrict__ BpO, float* __restrict__ CpO,
    int M, int N, int K)
{
    __shared__ __align__(16) char lsa[8192];   // A tile [128][32] bf16
    __shared__ __align__(16) char lsb[8192];   // Bt tile [128][32] bf16

    const int tid = threadIdx.x;
    const int lane = tid & 63;
    const int w = tid >> 6, wr = w >> 1, wc = w & 1;
    const int row0 = blockIdx.y * 128, col0 = blockIdx.x * 128;
    const int rl = lane & 15, q = lane >> 4;

    const int srow = tid >> 2, schunk = tid & 3;
    const int Pw0 = SWZ(tid * 16);
    const int Pw1 = SWZ(4096 + tid * 16);

    int LA[4], LB[4];
#pragma unroll
    for (int m = 0; m < 4; ++m) LA[m] = SWZ((wr * 64 + m * 16 + rl) * 64 + q * 16);
#pragma unroll
    for (int n = 0; n < 4; ++n) LB[n] = SWZ((wc * 64 + n * 16 + rl) * 64 + q * 16);

    const ushort_t* pA = A + (size_t)(row0 + srow) * K + schunk * 8;
    const ushort_t* pB = Bt + (size_t)(col0 + srow) * K + schunk * 8;
    const size_t rowskip = (size_t)64 * K;

    short8 ra0 = *(const short8*)(pA);
    short8 ra1 = *(const short8*)(pA + rowskip);
    short8 rb0 = *(const short8*)(pB);
    short8 rb1 = *(const short8*)(pB + rowskip);

    f32x4 acc[4][4] = {};

    const int NT = K >> 5;
    for (int kt = 0; kt < NT; ++kt) {
        __syncthreads();
        *(short8*)(lsa + Pw0) = ra0;
        *(short8*)(lsa + Pw1) = ra1;
        *(short8*)(lsb + Pw0) = rb0;
        *(short8*)(lsb + Pw1) = rb1;
        __syncthreads();
        if (kt + 1 < NT) {
            const ushort_t* nA = pA + (size_t)(kt + 1) * 32;
            const ushort_t* nB = pB + (size_t)(kt + 1) * 32;
            ra0 = *(const short8*)(nA);
            ra1 = *(const short8*)(nA + rowskip);
            rb0 = *(const short8*)(nB);
            rb1 = *(const short8*)(nB + rowskip);
        }
        short8 af[4], bfr[4];
#pragma unroll
        for (int m = 0; m < 4; ++m) af[m] = *(const short8*)(lsa + LA[m]);
#pragma unroll
        for (int n = 0; n < 4; ++n) bfr[n] = *(const short8*)(lsb + LB[n]);
#pragma unroll
        for (int m = 0; m < 4; ++m)
#pragma unroll
            for (int n = 0; n < 4; ++n)
                acc[m][n] = __builtin_amdgcn_mfma_f32_16x16x32_bf16(
                    af[m], bfr[n], acc[m][n], 0, 0, 0);
    }

    float bia[4];
#pragma unroll
    for (int n = 0; n < 4; ++n) {
        int c = col0 + wc * 64 + n * 16 + rl;
        bia[n] = (HAS_BIAS && c < DM) ? bias[c] : 0.f;
    }
#pragma unroll
    for (int m = 0; m < 4; ++m) {
#pragma unroll
        for (int n = 0; n < 4; ++n) {
            int c = col0 + wc * 64 + n * 16 + rl;
#pragma unroll
            for (int i = 0; i < 4; ++i) {
                int r = row0 + wr * 64 + m * 16 + q * 4 + i;
                float v = acc[m][n][i];
                if (PROJ && c >= DM) {
                    if (c < DM + DS)          BpO[(size_t)r * DS + (c - DM)] = v;
                    else if (c < DM + 2 * DS) CpO[(size_t)r * DS + (c - DM - DS)] = v;
                } else {
                    v += bia[n];
                    if (ACT == 1) v = sp_f(v);
                    if (HAS_RES) v += res[(size_t)r * N + c];
                    if (OUTBF) ((ushort_t*)Cout)[(size_t)r * N + c] = f2bf(v);
                    else       ((float*)Cout)[(size_t)r * N + c] = v;
                }
            }
        }
    }
}

// ---------------------------------------------------------------------------
// Transpose-convert: in[K][N] fp32 -> out[N][K] bf16
// ---------------------------------------------------------------------------
__global__ __launch_bounds__(256) void tconv_k(
    const float* __restrict__ in, ushort_t* __restrict__ out, int K, int N)
{
    __shared__ float t[32][33];
    int lx = threadIdx.x & 31, ly = threadIdx.x >> 5;
    int n0 = blockIdx.x * 32, k0 = blockIdx.y * 32;
#pragma unroll
    for (int i = 0; i < 32; i += 8)
        t[ly + i][lx] = in[(size_t)(k0 + ly + i) * N + n0 + lx];
    __syncthreads();
#pragma unroll
    for (int i = 0; i < 32; i += 8)
        out[(size_t)(n0 + ly + i) * K + k0 + lx] = f2bf(t[lx][ly + i]);
}

// rows [DM, DM+128) of WdcT: W_B^T, W_C^T, zeros
__global__ __launch_bounds__(256) void tail_pack_k(
    const float* __restrict__ WB, const float* __restrict__ WC,
    ushort_t* __restrict__ WdcT)
{
    int t = blockIdx.x * 256 + threadIdx.x;   // 128*1024
    int k = t & (DM - 1);
    int r = t >> 10;                          // 0..127
    ushort_t v = 0;
    if (r < DS)          v = f2bf(WB[(size_t)k * DS + r]);
    else if (r < 2 * DS) v = f2bf(WC[(size_t)k * DS + (r - DS)]);
    WdcT[(size_t)(DM + r) * DM + k] = v;
}

// elementwise fp32 -> bf16 (4/thread)
__global__ __launch_bounds__(256) void cvt_bf_k(
    const float* __restrict__ in, ushort_t* __restrict__ out)
{
    int t = blockIdx.x * 256 + threadIdx.x;
    f4 v = ((const f4*)in)[t];
    us4 o;
    o.x = f2bf(v.x); o.y = f2bf(v.y); o.z = f2bf(v.z); o.w = f2bf(v.w);
    ((us4*)out)[t] = o;
}

// ---------------------------------------------------------------------------
// Depthwise conv1d (K=3, same padding) + SiLU.  bf16 in (z), bf16 out (val).
// ---------------------------------------------------------------------------
__global__ __launch_bounds__(256) void conv_silu_k(
    const ushort_t* __restrict__ z_bf, const float* __restrict__ cw,
    ushort_t* __restrict__ val_bf)
{
    int t = blockIdx.x * 256 + threadIdx.x;    // ROWS*DI/4
    int c0 = (t & 255) * 4;
    int row = t >> 8;
    int l = row & (LL - 1);
    const ushort_t* zr = z_bf + (size_t)row * (2 * DI) + c0;
    us4 zz = {0, 0, 0, 0};
    us4 vm = (l > 0)      ? *(const us4*)(zr - 2 * DI) : zz;
    us4 v0 = *(const us4*)(zr);
    us4 vp = (l < LL - 1) ? *(const us4*)(zr + 2 * DI) : zz;
    const f4* wp = (const f4*)(cw + (size_t)c0 * 3);
    f4 w0 = wp[0], w1 = wp[1], w2 = wp[2];
    float w[12];
#pragma unroll
    for (int k = 0; k < 4; ++k) { w[k] = w0[k]; w[4 + k] = w1[k]; w[8 + k] = w2[k]; }
    us4 o;
#pragma unroll
    for (int j = 0; j < 4; ++j) {
        float s = bf2f(vm[j]) * w[3 * j] + bf2f(v0[j]) * w[3 * j + 1]
                + bf2f(vp[j]) * w[3 * j + 2];
        float si = s / (1.f + __expf(-s));
        o[j] = f2bf(si);
    }
    *(us4*)(val_bf + (size_t)row * DI + c0) = o;
}

// ---------------------------------------------------------------------------
// Chunked selective scan, thread per (b,d,chunk), 16 n in registers.
// h = a*(h+t) - t with t = (B/A)*u;  a = exp(Delta*A).
// ---------------------------------------------------------------------------
__global__ __launch_bounds__(256) void scan_p1_k(
    const ushort_t* __restrict__ Del_bf, const ushort_t* __restrict__ val_bf,
    const float* __restrict__ Bp, const float* __restrict__ A_log,
    float* __restrict__ aprod, float* __restrict__ hloc)
{
    int t = blockIdx.x * 256 + threadIdx.x;    // BB*NCH*DI = 131072
    int d = t & (DI - 1);
    int c = (t >> 10) & (NCH - 1);
    int b = t >> 16;

    float Adn[DS], ci[DS];
    const f4* alp = (const f4*)(A_log + (size_t)d * DS);
#pragma unroll
    for (int j = 0; j < 4; ++j) {
        f4 al = alp[j];
#pragma unroll
        for (int k = 0; k < 4; ++k) {
            float a = -__expf(al[k]);
            Adn[j * 4 + k] = a;
            ci[j * 4 + k] = 1.0f / a;
        }
    }
    int row0 = b * LL + c * CH;
    const ushort_t* Dp = Del_bf + (size_t)row0 * DI + d;
    const ushort_t* up = val_bf + (size_t)row0 * DI + d;
    const f4* bp = (const f4*)(Bp + (size_t)row0 * DS);

    float h[DS];
#pragma unroll
    for (int n = 0; n < DS; ++n) h[n] = 0.f;
    float sdv = 0.f;

#pragma unroll 2
    for (int l = 0; l < CH; ++l) {
        float dv = bf2f(Dp[(size_t)l * DI]);
        float u  = bf2f(up[(size_t)l * DI]);
        f4 q0 = bp[l * 4 + 0], q1 = bp[l * 4 + 1], q2 = bp[l * 4 + 2], q3 = bp[l * 4 + 3];
        float bn[DS];
#pragma unroll
        for (int k = 0; k < 4; ++k) {
            bn[k] = q0[k]; bn[4 + k] = q1[k]; bn[8 + k] = q2[k]; bn[12 + k] = q3[k];
        }
        sdv += dv;
#pragma unroll
        for (int n = 0; n < DS; ++n) {
            float a  = __expf(dv * Adn[n]);
            float tt = (ci[n] * bn[n]) * u;
            float s  = h[n] + tt;
            h[n] = fmaf(a, s, -tt);
        }
    }
    size_t o = (((size_t)b * NCH + c) * DI + d) * DS;
#pragma unroll
    for (int j = 0; j < 4; ++j) {
        f4 hv, av;
#pragma unroll
        for (int k = 0; k < 4; ++k) {
            hv[k] = h[j * 4 + k];
            av[k] = __expf(sdv * Adn[j * 4 + k]);
        }
        *(f4*)(hloc + o + j * 4) = hv;
        *(f4*)(aprod + o + j * 4) = av;
    }
}

__global__ __launch_bounds__(256) void scan_p2_k(
    const float* __restrict__ aprod, const float* __restrict__ hloc,
    float* __restrict__ hin)
{
    int t = blockIdx.x * 256 + threadIdx.x;    // BB*DI*DS = 32768
    int dn = t & (DI * DS - 1);
    int b = t >> 14;
    float h = 0.f;
    size_t base = (size_t)b * NCH * DI * DS + dn;
#pragma unroll 4
    for (int c = 0; c < NCH; ++c) {
        size_t idx = base + (size_t)c * (DI * DS);
        hin[idx] = h;
        h = fmaf(aprod[idx], h, hloc[idx]);
    }
}

// phase 3: recompute with correct h_in; fused gate: g_bf = bf16(y * silu(zgate))
__global__ __launch_bounds__(256) void scan_p3_k(
    const ushort_t* __restrict__ Del_bf, const ushort_t* __restrict__ val_bf,
    const float* __restrict__ Bp, const float* __restrict__ Cp,
    const float* __restrict__ A_log, const float* __restrict__ hin,
    const ushort_t* __restrict__ z_bf, ushort_t* __restrict__ g_bf)
{
    int t = blockIdx.x * 256 + threadIdx.x;    // BB*NCH*DI
    int d = t & (DI - 1);
    int c = (t >> 10) & (NCH - 1);
    int b = t >> 16;

    float Adn[DS], ci[DS];
    const f4* alp = (const f4*)(A_log + (size_t)d * DS);
#pragma unroll
    for (int j = 0; j < 4; ++j) {
        f4 al = alp[j];
#pragma unroll
        for (int k = 0; k < 4; ++k) {
            float a = -__expf(al[k]);
            Adn[j * 4 + k] = a;
            ci[j * 4 + k] = 1.0f / a;
        }
    }
    int row0 = b * LL + c * CH;
    const ushort_t* Dp = Del_bf + (size_t)row0 * DI + d;
    const ushort_t* up = val_bf + (size_t)row0 * DI + d;
    const ushort_t* zp = z_bf + (size_t)row0 * (2 * DI) + DI + d;
    const f4* bp = (const f4*)(Bp + (size_t)row0 * DS);
    const f4* cp = (const f4*)(Cp + (size_t)row0 * DS);
    ushort_t* gp = g_bf + (size_t)row0 * DI + d;

    float h[DS];
    size_t o = (((size_t)b * NCH + c) * DI + d) * DS;
#pragma unroll
    for (int j = 0; j < 4; ++j) {
        f4 hv = *(const f4*)(hin + o + j * 4);
#pragma unroll
        for (int k = 0; k < 4; ++k) h[j * 4 + k] = hv[k];
    }

#pragma unroll 2
    for (int l = 0; l < CH; ++l) {
        float dv = bf2f(Dp[(size_t)l * DI]);
        float u  = bf2f(up[(size_t)l * DI]);
        f4 q0 = bp[l * 4 + 0], q1 = bp[l * 4 + 1], q2 = bp[l * 4 + 2], q3 = bp[l * 4 + 3];
        f4 r0 = cp[l * 4 + 0], r1 = cp[l * 4 + 1], r2 = cp[l * 4 + 2], r3 = cp[l * 4 + 3];
        float bn[DS], cn[DS];
#pragma unroll
        for (int k = 0; k < 4; ++k) {
            bn[k] = q0[k]; bn[4 + k] = q1[k]; bn[8 + k] = q2[k]; bn[12 + k] = q3[k];
            cn[k] = r0[k]; cn[4 + k] = r1[k]; cn[8 + k] = r2[k]; cn[12 + k] = r3[k];
        }
        float psum = 0.f;
#pragma unroll
        for (int n = 0; n < DS; ++n) {
            float a  = __expf(dv * Adn[n]);
            float tt = (ci[n] * bn[n]) * u;
            float s  = h[n] + tt;
            h[n] = fmaf(a, s, -tt);
            psum = fmaf(h[n], cn[n], psum);
        }
        float zg = bf2f(zp[(size_t)l * 2 * DI]);
        float si = zg / (1.f + __expf(-zg));
        gp[(size_t)l * DI] = f2bf(psum * si);
    }
}

// ---------------------------------------------------------------------------
extern "C" void kernel_launch(void* const* d_in, const int* in_sizes, int n_in,
                              void* d_out, int out_size, void* d_ws, size_t ws_size,
                              hipStream_t stream)
{
    (void)in_sizes; (void)n_in; (void)out_size; (void)ws_size;

    const float* x        = (const float*)d_in[0];
    const float* W_in     = (const float*)d_in[1];
    const float* conv_w   = (const float*)d_in[2];
    const float* W_B      = (const float*)d_in[3];
    const float* W_C      = (const float*)d_in[4];
    const float* W_delta  = (const float*)d_in[5];
    const float* delta_b  = (const float*)d_in[6];
    const float* W_tau    = (const float*)d_in[7];
    const float* A_log    = (const float*)d_in[8];
    const float* W_out    = (const float*)d_in[9];
    float* out = (float*)d_out;

    const size_t M1 = 1024 * 1024;
    ushort_t* us = (ushort_t*)d_ws;
    ushort_t* z_bf   = us;                    // 4M sh
    ushort_t* val_bf = us + 4 * M1;           // 2M
    ushort_t* cmb_bf = us + 6 * M1;           // 2M
    ushort_t* Del_bf = us + 8 * M1;           // 2M
    ushort_t* x_bf   = us + 10 * M1;          // 2M
    ushort_t* g_bf   = us + 12 * M1;          // 2M
    ushort_t* WinT   = us + 14 * M1;          // 2M
    ushort_t* WdcT   = us + 16 * M1;          // NP*DM = 1.125M
    ushort_t* WtT    = us + 16 * M1 + (size_t)NP * DM;   // 1M
    ushort_t* WoT    = WtT + M1;              // 1M  (ends ~38.3MB)
    float* fb   = (float*)(us + 20 * M1);     // 40MB offset
    float* Bp    = fb;                        // 32K fl
    float* Cp    = fb + (size_t)ROWS * DS;    // 32K fl
    float* aprod = fb + 2 * (size_t)ROWS * DS; // 2M fl
    float* hloc  = aprod + 2 * M1;            // 2M fl
    float* hin   = hloc + 2 * M1;             // 2M fl (ends ~64.3MB)

    // 0) converts / weight transposes
    cvt_bf_k<<<(ROWS * DM / 4) / 256, 256, 0, stream>>>(x, x_bf);
    tconv_k<<<dim3(2 * DI / 32, DM / 32), 256, 0, stream>>>(W_in, WinT, DM, 2 * DI);
    tconv_k<<<dim3(DM / 32, DI / 32), 256, 0, stream>>>(W_delta, WdcT, DI, DM);
    tail_pack_k<<<(128 * DM) / 256, 256, 0, stream>>>(W_B, W_C, WdcT);
    tconv_k<<<dim3(DM / 32, DM / 32), 256, 0, stream>>>(W_tau, WtT, DM, DM);
    tconv_k<<<dim3(DM / 32, DI / 32), 256, 0, stream>>>(W_out, WoT, DI, DM);

    // 1) z = x @ W_in  (bf16 out)
    gemm_bf_k<0, false, false, true, false><<<dim3(2 * DI / 128, ROWS / 128), 256, 0, stream>>>(
        x_bf, WinT, nullptr, nullptr, z_bf, nullptr, nullptr, ROWS, 2 * DI, DM);

    // 2) val = silu(conv1d(z[:, :DI]))
    conv_silu_k<<<(ROWS * DI / 4) / 256, 256, 0, stream>>>(z_bf, conv_w, val_bf);

    // 3+4) combined = val @ W_delta + delta_base (bf16) ; fused B/C projections (fp32)
    gemm_bf_k<0, true, false, true, true><<<dim3(NP / 128, ROWS / 128), 256, 0, stream>>>(
        val_bf, WdcT, delta_b, nullptr, cmb_bf, Bp, Cp, ROWS, NP, DI);

    // 5) Delta = softplus(combined @ W_tau) (bf16)
    gemm_bf_k<1, false, false, true, false><<<dim3(DM / 128, ROWS / 128), 256, 0, stream>>>(
        cmb_bf, WtT, nullptr, nullptr, Del_bf, nullptr, nullptr, ROWS, DM, DM);

    // 6) chunked selective scan; p3 fuses gate -> g_bf
    scan_p1_k<<<(BB * NCH * DI) / 256, 256, 0, stream>>>(
        Del_bf, val_bf, Bp, A_log, aprod, hloc);
    scan_p2_k<<<(BB * DI * DS) / 256, 256, 0, stream>>>(aprod, hloc, hin);
    scan_p3_k<<<(BB * NCH * DI) / 256, 256, 0, stream>>>(
        Del_bf, val_bf, Bp, Cp, A_log, hin, z_bf, g_bf);

    // 7) out = g @ W_out + x (fp32 out)
    gemm_bf_k<0, false, true, false, false><<<dim3(DM / 128, ROWS / 128), 256, 0, stream>>>(
        g_bf, WoT, nullptr, x, out, nullptr, nullptr, ROWS, DM, DI);
}